// Round 1
// baseline (728.416 us; speedup 1.0000x reference)
//
#include <hip/hip_runtime.h>
#include <math.h>

#define MATCH_THRESH 0.5f
#define THETA 0.99f
#define NEG_INF_F (-1e30f)

// ---------- device helpers ----------

__device__ __forceinline__ float iou_pf(
    float ax1, float ay1, float ax2, float ay2,
    float bx1, float by1, float bx2, float by2) {
  float lx = fmaxf(ax1, bx1), ly = fmaxf(ay1, by1);
  float rx = fminf(ax2, bx2), ry = fminf(ay2, by2);
  float w = fmaxf(rx - lx, 0.f), h = fmaxf(ry - ly, 0.f);
  float inter = w * h;
  float aa = (ax2 - ax1) * (ay2 - ay1);
  float ab = (bx2 - bx1) * (by2 - by1);
  return inter / (aa + ab - inter);
}

__device__ __forceinline__ float sl1(float x) {
  float a = fabsf(x);
  return (a < 1.f) ? 0.5f * a * a : a - 0.5f;
}

__device__ __forceinline__ float wredf(float v) {
#pragma unroll
  for (int o = 32; o > 0; o >>= 1) v += __shfl_down(v, o, 64);
  return v;
}

__device__ __forceinline__ int wredi(int v) {
#pragma unroll
  for (int o = 32; o > 0; o >>= 1) v += __shfl_down(v, o, 64);
  return v;
}

// ---------- kernel 1/2: per-GT argmax over anchors (first occurrence) ----------

template <bool REFINED>
__global__ void gt_best_anchor_kernel(const float* __restrict__ gt_boxes,   // [B,M,4] point form
                                      const float* __restrict__ anchors,    // [A,4] center form
                                      const float* __restrict__ refine_loc, // [B,A,4] (REFINED only)
                                      int* __restrict__ best_anchor,        // [B,M]
                                      int B, int M, int A) {
  int bm = blockIdx.x;
  int b = bm / M;
  const float* g = gt_boxes + (size_t)bm * 4;
  float gx1 = g[0], gy1 = g[1], gx2 = g[2], gy2 = g[3];
  float best = -1.f;
  int bi = 0x7fffffff;
  for (int a = threadIdx.x; a < A; a += blockDim.x) {
    const float* an = anchors + (size_t)a * 4;
    float cx = an[0], cy = an[1], w = an[2], h = an[3];
    if (REFINED) {
      const float* rl = refine_loc + ((size_t)b * A + a) * 4;
      cx = cx + rl[0] * 0.1f * w;
      cy = cy + rl[1] * 0.1f * h;
      w = w * expf(rl[2] * 0.2f);
      h = h * expf(rl[3] * 0.2f);
    }
    float v = iou_pf(gx1, gy1, gx2, gy2,
                     cx - w * 0.5f, cy - h * 0.5f, cx + w * 0.5f, cy + h * 0.5f);
    if (v > best) { best = v; bi = a; }  // strict > keeps smallest index in stride set
  }
  __shared__ float sv[256];
  __shared__ int si[256];
  sv[threadIdx.x] = best;
  si[threadIdx.x] = bi;
  __syncthreads();
  for (int s = blockDim.x / 2; s > 0; s >>= 1) {
    if (threadIdx.x < s) {
      float ov = sv[threadIdx.x + s];
      int oi = si[threadIdx.x + s];
      if (ov > sv[threadIdx.x] || (ov == sv[threadIdx.x] && oi < si[threadIdx.x])) {
        sv[threadIdx.x] = ov;
        si[threadIdx.x] = oi;
      }
    }
    __syncthreads();
  }
  if (threadIdx.x == 0) best_anchor[bm] = si[0];
}

// ---------- kernel 3: ARM stage losses ----------

__global__ void arm_loss_kernel(const float* __restrict__ gt_boxes,
                                const int* __restrict__ gt_labels,
                                const float* __restrict__ anchors,
                                const float* __restrict__ refine_loc,
                                const float* __restrict__ objectness,
                                const int* __restrict__ best_anchor1,
                                double* __restrict__ acc,  // [0]=arm_loc,[1]=arm_cls
                                int* __restrict__ iacc,    // [0]=arm_N
                                int B, int M, int A) {
  int b = blockIdx.y;
  int a = blockIdx.x * blockDim.x + threadIdx.x;
  float loc_sum = 0.f, cls_sum = 0.f;
  int pos_i = 0;
  if (a < A) {
    const float* an = anchors + (size_t)a * 4;
    float acx = an[0], acy = an[1], aw = an[2], ah = an[3];
    float ax1 = acx - aw * 0.5f, ay1 = acy - ah * 0.5f;
    float ax2 = acx + aw * 0.5f, ay2 = acy + ah * 0.5f;
    const float* gb = gt_boxes + (size_t)b * M * 4;
    float best = -1.f;
    int bi = 0;
    for (int m = 0; m < M; m++) {
      float v = iou_pf(gb[m * 4], gb[m * 4 + 1], gb[m * 4 + 2], gb[m * 4 + 3],
                       ax1, ay1, ax2, ay2);
      if (v > best) { best = v; bi = m; }
    }
    const int* ba = best_anchor1 + b * M;
    for (int m = 0; m < M; m++)
      if (ba[m] == a) { bi = m; best = 2.0f; }  // ascending: last write wins
    int conf = (best < MATCH_THRESH) ? 0 : gt_labels[b * M + bi];
    int pos = conf > 0;
    if (pos) {
      const float* g = gb + bi * 4;
      float gcx = ((g[0] + g[2]) * 0.5f - acx) / (0.1f * aw);
      float gcy = ((g[1] + g[3]) * 0.5f - acy) / (0.1f * ah);
      float gw = logf((g[2] - g[0]) / aw) / 0.2f;
      float gh = logf((g[3] - g[1]) / ah) / 0.2f;
      const float* rl = refine_loc + ((size_t)b * A + a) * 4;
      loc_sum = sl1(rl[0] - gcx) + sl1(rl[1] - gcy) + sl1(rl[2] - gw) + sl1(rl[3] - gh);
    }
    const float* ob = objectness + ((size_t)b * A + a) * 2;
    float o0 = ob[0], o1 = ob[1];
    float mx = fmaxf(o0, o1);
    float lse = mx + logf(expf(o0 - mx) + expf(o1 - mx));
    cls_sum = lse - (pos ? o1 : o0);
    pos_i = pos;
  }
  float l = wredf(loc_sum);
  float c = wredf(cls_sum);
  int p = wredi(pos_i);
  if ((threadIdx.x & 63) == 0) {
    if (l != 0.f) atomicAdd(&acc[0], (double)l);
    atomicAdd(&acc[1], (double)c);
    if (p) atomicAdd(&iacc[0], p);
  }
}

// ---------- kernel 4: ODM stage losses + neg_losses ----------

__global__ void odm_loss_kernel(const float* __restrict__ gt_boxes,
                                const int* __restrict__ gt_labels,
                                const float* __restrict__ anchors,
                                const float* __restrict__ refine_loc,
                                const float* __restrict__ objectness,
                                const float* __restrict__ pred_conf,
                                const float* __restrict__ pred_loc,
                                const int* __restrict__ best_anchor2,
                                double* __restrict__ acc,     // [2]=loc,[3]=ce_pos
                                int* __restrict__ poscnt,     // [B]
                                float* __restrict__ neg_losses, // [B,A]
                                int B, int M, int A, int C) {
  int b = blockIdx.y;
  int a = blockIdx.x * blockDim.x + threadIdx.x;
  float loc_sum = 0.f, ce_pos = 0.f;
  int pos_i = 0;
  if (a < A) {
    const float* an = anchors + (size_t)a * 4;
    const float* rl = refine_loc + ((size_t)b * A + a) * 4;
    float rcx = an[0] + rl[0] * 0.1f * an[2];
    float rcy = an[1] + rl[1] * 0.1f * an[3];
    float rw = an[2] * expf(rl[2] * 0.2f);
    float rh = an[3] * expf(rl[3] * 0.2f);
    float rx1 = rcx - rw * 0.5f, ry1 = rcy - rh * 0.5f;
    float rx2 = rcx + rw * 0.5f, ry2 = rcy + rh * 0.5f;
    const float* gb = gt_boxes + (size_t)b * M * 4;
    float best = -1.f;
    int bi = 0;
    for (int m = 0; m < M; m++) {
      float v = iou_pf(gb[m * 4], gb[m * 4 + 1], gb[m * 4 + 2], gb[m * 4 + 3],
                       rx1, ry1, rx2, ry2);
      if (v > best) { best = v; bi = m; }
    }
    const int* ba = best_anchor2 + b * M;
    for (int m = 0; m < M; m++)
      if (ba[m] == a) { bi = m; best = 2.0f; }
    int conf2 = (best < MATCH_THRESH) ? 0 : gt_labels[b * M + bi];
    // object mask: softmax(objectness)[...,0] < THETA
    const float* ob = objectness + ((size_t)b * A + a) * 2;
    float o0 = ob[0], o1 = ob[1];
    float mx = fmaxf(o0, o1);
    float e0 = expf(o0 - mx), e1 = expf(o1 - mx);
    bool mask = (e0 / (e0 + e1)) < THETA;
    int pos2 = (conf2 > 0) && mask;
    // 21-class CE
    const float* pc = pred_conf + ((size_t)b * A + a) * C;
    float x[32];
    float mxc = -INFINITY;
    for (int c = 0; c < C; c++) { x[c] = pc[c]; mxc = fmaxf(mxc, x[c]); }
    float s = 0.f;
    for (int c = 0; c < C; c++) s += expf(x[c] - mxc);
    float ce = mxc + logf(s) - x[conf2];
    if (pos2) {
      const float* g = gb + bi * 4;
      float gcx = ((g[0] + g[2]) * 0.5f - rcx) / (0.1f * rw);
      float gcy = ((g[1] + g[3]) * 0.5f - rcy) / (0.1f * rh);
      float gw = logf((g[2] - g[0]) / rw) / 0.2f;
      float gh = logf((g[3] - g[1]) / rh) / 0.2f;
      const float* pl = pred_loc + ((size_t)b * A + a) * 4;
      loc_sum = sl1(pl[0] - gcx) + sl1(pl[1] - gcy) + sl1(pl[2] - gw) + sl1(pl[3] - gh);
      ce_pos = ce;
      pos_i = 1;
    }
    neg_losses[(size_t)b * A + a] = (mask && conf2 == 0) ? ce : NEG_INF_F;
  }
  float l = wredf(loc_sum);
  float c = wredf(ce_pos);
  int p = wredi(pos_i);
  if ((threadIdx.x & 63) == 0) {
    if (l != 0.f) atomicAdd(&acc[2], (double)l);
    if (c != 0.f) atomicAdd(&acc[3], (double)c);
    if (p) atomicAdd(&poscnt[b], p);
  }
}

// ---------- kernel 5: per-batch hard-negative mining (bitonic sort in LDS) ----------

__global__ __launch_bounds__(1024) void hardneg_kernel(const float* __restrict__ neg_losses,
                                                       const int* __restrict__ poscnt,
                                                       double* __restrict__ acc,  // [4]=neg_sum
                                                       int A, int n /* pow2 >= A, <= 16384 */) {
  __shared__ float s[16384];
  int b = blockIdx.x;
  const float* nl = neg_losses + (size_t)b * A;
  for (int i = threadIdx.x; i < n; i += blockDim.x) s[i] = (i < A) ? nl[i] : NEG_INF_F;
  __syncthreads();
  // ascending bitonic sort
  for (int k = 2; k <= n; k <<= 1) {
    for (int j = k >> 1; j > 0; j >>= 1) {
      for (int i = threadIdx.x; i < n; i += blockDim.x) {
        int ixj = i ^ j;
        if (ixj > i) {
          float va = s[i], vb = s[ixj];
          bool up = ((i & k) == 0);
          if (up ? (va > vb) : (va < vb)) { s[i] = vb; s[ixj] = va; }
        }
      }
      __syncthreads();
    }
  }
  int pn = poscnt[b];
  int nn = max(10, min(pn * 3, A - pn));
  float partial = 0.f;
  for (int t = threadIdx.x; t < nn; t += blockDim.x) {
    float v = s[n - 1 - t];  // top-K from the ascending tail
    if (v > NEG_INF_F * 0.5f) partial += v;
  }
  __syncthreads();
  s[threadIdx.x] = partial;
  __syncthreads();
  for (int st = blockDim.x / 2; st > 0; st >>= 1) {
    if (threadIdx.x < st) s[threadIdx.x] += s[threadIdx.x + st];
    __syncthreads();
  }
  if (threadIdx.x == 0) atomicAdd(&acc[4], (double)s[0]);
}

// ---------- kernel 6: finalize ----------

__global__ void finalize_kernel(const double* __restrict__ acc,
                                const int* __restrict__ iacc,
                                const int* __restrict__ poscnt,
                                int B, float* __restrict__ out) {
  if (threadIdx.x != 0 || blockIdx.x != 0) return;
  double arm_loc = acc[0], arm_cls = acc[1], odm_loc = acc[2];
  double ce_pos = acc[3], neg_sum = acc[4];
  double armN = (double)iacc[0];
  long long Ni = 0;
  for (int b = 0; b < B; b++) Ni += poscnt[b];
  double N = (double)Ni;
  double class_loss = (ce_pos + neg_sum) / N;
  double loc_loss = odm_loc / N;
  double acls = 0.04 * arm_cls / armN;
  double aloc = arm_loc / armN;
  double total = class_loss + loc_loss + acls + aloc;
  out[0] = (float)total;
  out[1] = (float)class_loss;
  out[2] = (float)loc_loss;
  out[3] = (float)acls;
  out[4] = (float)aloc;
}

// ---------- launcher ----------

extern "C" void kernel_launch(void* const* d_in, const int* in_sizes, int n_in,
                              void* d_out, int out_size, void* d_ws, size_t ws_size,
                              hipStream_t stream) {
  const float* objectness = (const float*)d_in[0];
  const float* refine_loc = (const float*)d_in[1];
  const float* pred_conf  = (const float*)d_in[2];
  const float* pred_loc   = (const float*)d_in[3];
  const float* anchors    = (const float*)d_in[4];  // [1,A,4]
  const float* gt_boxes   = (const float*)d_in[5];
  const int*   gt_labels  = (const int*)d_in[6];

  int A = in_sizes[4] / 4;
  int B = in_sizes[0] / (A * 2);
  int C = (int)(in_sizes[2] / ((long long)B * A));
  int M = in_sizes[5] / (B * 4);

  char* ws = (char*)d_ws;
  // layout: [0,64): double acc[5] (arm_loc, arm_cls, odm_loc, ce_pos, neg_sum)
  //         [64,128): int iacc (arm_N)
  //         [128,128+4B): int poscnt[B]
  //         [512, 512+4BM): best_anchor1
  //         [512+4BM, 512+8BM): best_anchor2
  //         then: neg_losses[B*A] floats
  double* acc = (double*)ws;
  int* iacc = (int*)(ws + 64);
  int* poscnt = (int*)(ws + 128);
  size_t zero_bytes = 512;
  int* ba1 = (int*)(ws + 512);
  int* ba2 = (int*)(ws + 512 + (size_t)B * M * 4);
  size_t negl_off = 512 + 2 * (size_t)B * M * 4;
  negl_off = (negl_off + 255) & ~(size_t)255;
  float* negl = (float*)(ws + negl_off);

  hipMemsetAsync(d_ws, 0, zero_bytes, stream);

  gt_best_anchor_kernel<false><<<B * M, 256, 0, stream>>>(gt_boxes, anchors, nullptr, ba1, B, M, A);
  gt_best_anchor_kernel<true><<<B * M, 256, 0, stream>>>(gt_boxes, anchors, refine_loc, ba2, B, M, A);

  dim3 grid((A + 255) / 256, B);
  arm_loss_kernel<<<grid, 256, 0, stream>>>(gt_boxes, gt_labels, anchors, refine_loc,
                                            objectness, ba1, acc, iacc, B, M, A);
  odm_loss_kernel<<<grid, 256, 0, stream>>>(gt_boxes, gt_labels, anchors, refine_loc,
                                            objectness, pred_conf, pred_loc, ba2,
                                            acc, poscnt, negl, B, M, A, C);

  int n = 1;
  while (n < A) n <<= 1;
  if (n > 16384) n = 16384;  // problem-size guard (A=16320 fits)
  hardneg_kernel<<<B, 1024, 0, stream>>>(negl, poscnt, acc, A, n);

  finalize_kernel<<<1, 1, 0, stream>>>(acc, iacc, poscnt, B, (float*)d_out);
}

// Round 2
// 166.130 us; speedup vs baseline: 4.3846x; 4.3846x over previous
//
#include <hip/hip_runtime.h>
#include <math.h>

#define MATCH_THRESH 0.5f
#define THETA 0.99f
#define NEG_INF_F (-1e30f)

// ---------- device helpers ----------

__device__ __forceinline__ float iou_pf(
    float ax1, float ay1, float ax2, float ay2,
    float bx1, float by1, float bx2, float by2) {
  float lx = fmaxf(ax1, bx1), ly = fmaxf(ay1, by1);
  float rx = fminf(ax2, bx2), ry = fminf(ay2, by2);
  float w = fmaxf(rx - lx, 0.f), h = fmaxf(ry - ly, 0.f);
  float inter = w * h;
  float aa = (ax2 - ax1) * (ay2 - ay1);
  float ab = (bx2 - bx1) * (by2 - by1);
  return inter / (aa + ab - inter);
}

__device__ __forceinline__ float sl1(float x) {
  float a = fabsf(x);
  return (a < 1.f) ? 0.5f * a * a : a - 0.5f;
}

__device__ __forceinline__ float wredf(float v) {
#pragma unroll
  for (int o = 32; o > 0; o >>= 1) v += __shfl_down(v, o, 64);
  return v;
}

__device__ __forceinline__ int wredi(int v) {
#pragma unroll
  for (int o = 32; o > 0; o >>= 1) v += __shfl_down(v, o, 64);
  return v;
}

// monotone key: descending float order == descending uint order
__device__ __forceinline__ unsigned fkey(float v) {
  unsigned b = __float_as_uint(v);
  return (b & 0x80000000u) ? ~b : (b | 0x80000000u);
}
__device__ __forceinline__ float keyf(unsigned u) {
  unsigned b = (u & 0x80000000u) ? (u & 0x7fffffffu) : ~u;
  return __uint_as_float(b);
}

// ---------- kernel 1/2: per-GT argmax over anchors (first occurrence) ----------

template <bool REFINED>
__global__ void gt_best_anchor_kernel(const float* __restrict__ gt_boxes,   // [B,M,4] point form
                                      const float* __restrict__ anchors,    // [A,4] center form
                                      const float* __restrict__ refine_loc, // [B,A,4]
                                      int* __restrict__ best_anchor,        // [B,M]
                                      int B, int M, int A) {
  int bm = blockIdx.x;
  int b = bm / M;
  const float* g = gt_boxes + (size_t)bm * 4;
  float gx1 = g[0], gy1 = g[1], gx2 = g[2], gy2 = g[3];
  const float4* an4 = (const float4*)anchors;
  const float4* rl4 = (const float4*)refine_loc + (size_t)b * A;
  float best = -1.f;
  int bi = 0x7fffffff;
  for (int a = threadIdx.x; a < A; a += blockDim.x) {
    float4 an = an4[a];
    float cx = an.x, cy = an.y, w = an.z, h = an.w;
    if (REFINED) {
      float4 rl = rl4[a];
      cx += rl.x * 0.1f * w;
      cy += rl.y * 0.1f * h;
      w *= expf(rl.z * 0.2f);
      h *= expf(rl.w * 0.2f);
    }
    float v = iou_pf(gx1, gy1, gx2, gy2,
                     cx - w * 0.5f, cy - h * 0.5f, cx + w * 0.5f, cy + h * 0.5f);
    if (v > best) { best = v; bi = a; }  // strict > keeps smallest index in stride set
  }
  __shared__ float sv[256];
  __shared__ int si[256];
  sv[threadIdx.x] = best;
  si[threadIdx.x] = bi;
  __syncthreads();
  for (int s = blockDim.x / 2; s > 0; s >>= 1) {
    if (threadIdx.x < s) {
      float ov = sv[threadIdx.x + s];
      int oi = si[threadIdx.x + s];
      if (ov > sv[threadIdx.x] || (ov == sv[threadIdx.x] && oi < si[threadIdx.x])) {
        sv[threadIdx.x] = ov;
        si[threadIdx.x] = oi;
      }
    }
    __syncthreads();
  }
  if (threadIdx.x == 0) best_anchor[bm] = si[0];
}

// ---------- kernel 3: fused ARM + ODM losses ----------

__global__ __launch_bounds__(256) void loss_kernel(
    const float* __restrict__ gt_boxes, const int* __restrict__ gt_labels,
    const float* __restrict__ anchors, const float* __restrict__ refine_loc,
    const float* __restrict__ objectness, const float* __restrict__ pred_conf,
    const float* __restrict__ pred_loc,
    const int* __restrict__ ba1, const int* __restrict__ ba2,
    double* __restrict__ acc,      // [0]=arm_loc [1]=arm_cls [2]=odm_loc [3]=ce_pos
    int* __restrict__ iacc,        // [0]=arm_N
    int* __restrict__ poscnt,      // [B]
    float* __restrict__ negl,      // [B,A]
    int B, int M, int A, int C) {
  int b = blockIdx.y;
  const float* gb = gt_boxes + (size_t)b * M * 4;
  const int* gl = gt_labels + (size_t)b * M;
  const int* b1 = ba1 + (size_t)b * M;
  const int* b2 = ba2 + (size_t)b * M;
  const float4* an4 = (const float4*)anchors;
  const float4* rl4 = (const float4*)refine_loc + (size_t)b * A;
  const float2* ob2 = (const float2*)objectness + (size_t)b * A;
  const float4* pl4 = (const float4*)pred_loc + (size_t)b * A;

  float p_arm_loc = 0.f, p_arm_cls = 0.f, p_loc = 0.f, p_cepos = 0.f;
  int p_armN = 0, p_pos2 = 0;

  int stride = gridDim.x * blockDim.x;
  for (int a = blockIdx.x * blockDim.x + threadIdx.x; a < A; a += stride) {
    float4 an = an4[a];
    float4 rl = rl4[a];
    float ax1 = an.x - an.z * 0.5f, ay1 = an.y - an.w * 0.5f;
    float ax2 = an.x + an.z * 0.5f, ay2 = an.y + an.w * 0.5f;
    float rcx = an.x + rl.x * 0.1f * an.z;
    float rcy = an.y + rl.y * 0.1f * an.w;
    float rw = an.z * expf(rl.z * 0.2f);
    float rh = an.w * expf(rl.w * 0.2f);
    float rx1 = rcx - rw * 0.5f, ry1 = rcy - rh * 0.5f;
    float rx2 = rcx + rw * 0.5f, ry2 = rcy + rh * 0.5f;

    float bestA = -1.f, bestR = -1.f;
    int biA = 0, biR = 0;
    for (int m = 0; m < M; m++) {
      float g0 = gb[m * 4], g1 = gb[m * 4 + 1], g2 = gb[m * 4 + 2], g3 = gb[m * 4 + 3];
      float vA = iou_pf(g0, g1, g2, g3, ax1, ay1, ax2, ay2);
      if (vA > bestA) { bestA = vA; biA = m; }
      float vR = iou_pf(g0, g1, g2, g3, rx1, ry1, rx2, ry2);
      if (vR > bestR) { bestR = vR; biR = m; }
    }
    for (int m = 0; m < M; m++) {   // guaranteed match: ascending, last write wins
      if (b1[m] == a) { biA = m; bestA = 2.f; }
      if (b2[m] == a) { biR = m; bestR = 2.f; }
    }
    int conf1 = (bestA < MATCH_THRESH) ? 0 : gl[biA];
    int conf2 = (bestR < MATCH_THRESH) ? 0 : gl[biR];
    int pos1 = conf1 > 0;

    // ARM loc loss (fixed anchors)
    if (pos1) {
      const float* g = gb + biA * 4;
      float gcx = ((g[0] + g[2]) * 0.5f - an.x) / (0.1f * an.z);
      float gcy = ((g[1] + g[3]) * 0.5f - an.y) / (0.1f * an.w);
      float gw = logf((g[2] - g[0]) / an.z) / 0.2f;
      float gh = logf((g[3] - g[1]) / an.w) / 0.2f;
      p_arm_loc += sl1(rl.x - gcx) + sl1(rl.y - gcy) + sl1(rl.z - gw) + sl1(rl.w - gh);
    }
    // ARM cls loss (2-class CE, all anchors)
    float2 ob = ob2[a];
    float mx = fmaxf(ob.x, ob.y);
    float e0 = expf(ob.x - mx), e1 = expf(ob.y - mx);
    float lse = mx + logf(e0 + e1);
    p_arm_cls += lse - (pos1 ? ob.y : ob.x);
    p_armN += pos1;

    // object mask
    bool mask = (e0 / (e0 + e1)) < THETA;
    int pos2 = (conf2 > 0) && mask;

    // 21-class CE via online softmax (no array -> no scratch)
    const float* pc = pred_conf + ((size_t)b * A + a) * C;
    float mxc = pc[0];
    float s = 1.f;
    for (int c = 1; c < C; c++) {
      float v = pc[c];
      float nm = fmaxf(mxc, v);
      s = s * expf(mxc - nm) + expf(v - nm);
      mxc = nm;
    }
    float ce = mxc + logf(s) - pc[conf2];

    if (pos2) {
      const float* g = gb + biR * 4;
      float gcx = ((g[0] + g[2]) * 0.5f - rcx) / (0.1f * rw);
      float gcy = ((g[1] + g[3]) * 0.5f - rcy) / (0.1f * rh);
      float gw = logf((g[2] - g[0]) / rw) / 0.2f;
      float gh = logf((g[3] - g[1]) / rh) / 0.2f;
      float4 pl = pl4[a];
      p_loc += sl1(pl.x - gcx) + sl1(pl.y - gcy) + sl1(pl.z - gw) + sl1(pl.w - gh);
      p_cepos += ce;
      p_pos2 += 1;
    }
    negl[(size_t)b * A + a] = (mask && conf2 == 0) ? ce : NEG_INF_F;
  }

  // per-wave then per-block reduce; ONE atomic per block per accumulator
  p_arm_loc = wredf(p_arm_loc); p_arm_cls = wredf(p_arm_cls);
  p_loc = wredf(p_loc); p_cepos = wredf(p_cepos);
  p_armN = wredi(p_armN); p_pos2 = wredi(p_pos2);
  __shared__ float sf[4][4];
  __shared__ int sw[2][4];
  int w = threadIdx.x >> 6;
  if ((threadIdx.x & 63) == 0) {
    sf[0][w] = p_arm_loc; sf[1][w] = p_arm_cls; sf[2][w] = p_loc; sf[3][w] = p_cepos;
    sw[0][w] = p_armN; sw[1][w] = p_pos2;
  }
  __syncthreads();
  if (threadIdx.x == 0) {
    float aL = 0, aC = 0, oL = 0, oC = 0;
    int aN = 0, p2 = 0;
    for (int i = 0; i < 4; i++) {
      aL += sf[0][i]; aC += sf[1][i]; oL += sf[2][i]; oC += sf[3][i];
      aN += sw[0][i]; p2 += sw[1][i];
    }
    if (aL != 0.f) atomicAdd(&acc[0], (double)aL);
    atomicAdd(&acc[1], (double)aC);
    if (oL != 0.f) atomicAdd(&acc[2], (double)oL);
    if (oC != 0.f) atomicAdd(&acc[3], (double)oC);
    if (aN) atomicAdd(&iacc[0], aN);
    if (p2) atomicAdd(&poscnt[b], p2);
  }
}

// ---------- kernel 4: top-K sum via exact binary search on float keys ----------
// Sum of top-K is tie-invariant: find kth-largest key u*, sum all > u*, add
// (K - count_gt) * value(u*). Values live in registers; counts via shfl+LDS.

__global__ __launch_bounds__(1024) void hardneg_kernel(
    const float* __restrict__ negl, const int* __restrict__ poscnt,
    double* __restrict__ acc, int A) {
  int b = blockIdx.x;
  const float* nl = negl + (size_t)b * A;
  int t = threadIdx.x;
  unsigned key[16];
#pragma unroll
  for (int j = 0; j < 16; j++) {
    int i = j * 1024 + t;
    key[j] = (i < A) ? fkey(nl[i]) : 0u;  // 0 sorts below everything
  }
  __shared__ int wcnt[16];
  __shared__ float wsum[16];
  int w = t >> 6;
  bool lane0 = (t & 63) == 0;

  const unsigned UVALID = fkey(-5e29f);  // NEG_INF/2 filter
  int cv = 0;
#pragma unroll
  for (int j = 0; j < 16; j++) cv += (key[j] > UVALID) ? 1 : 0;
  cv = wredi(cv);
  if (lane0) wcnt[w] = cv;
  __syncthreads();
  int cnt_valid = 0;
  for (int i = 0; i < 16; i++) cnt_valid += wcnt[i];

  int pn = poscnt[b];
  int nn = max(10, min(pn * 3, A - pn));
  int K = min(nn, cnt_valid);
  if (K <= 0) return;  // uniform across block

  // largest t such that count(key >= t) >= K  ==  K-th largest key
  unsigned lo = 0u, hi = 0xffffffffu;
  while (lo < hi) {
    unsigned d = hi - lo;
    unsigned mid = lo + (d >> 1) + (d & 1u);  // ceil, overflow-safe
    int c = 0;
#pragma unroll
    for (int j = 0; j < 16; j++) c += (key[j] >= mid) ? 1 : 0;
    c = wredi(c);
    __syncthreads();  // protect wcnt from previous iteration's readers
    if (lane0) wcnt[w] = c;
    __syncthreads();
    int tot = 0;
    for (int i = 0; i < 16; i++) tot += wcnt[i];
    if (tot >= K) lo = mid; else hi = mid - 1;
  }

  float kth = keyf(lo);
  float sum = 0.f;
  int c1 = 0;
#pragma unroll
  for (int j = 0; j < 16; j++) {
    if (key[j] > lo) { sum += keyf(key[j]); c1++; }
  }
  sum = wredf(sum);
  c1 = wredi(c1);
  __syncthreads();
  if (lane0) { wsum[w] = sum; wcnt[w] = c1; }
  __syncthreads();
  if (t == 0) {
    float S = 0.f;
    int C1 = 0;
    for (int i = 0; i < 16; i++) { S += wsum[i]; C1 += wcnt[i]; }
    S += (float)(K - C1) * kth;  // boundary ties
    atomicAdd(&acc[4], (double)S);
  }
}

// ---------- kernel 5: finalize ----------

__global__ void finalize_kernel(const double* __restrict__ acc,
                                const int* __restrict__ iacc,
                                const int* __restrict__ poscnt,
                                int B, float* __restrict__ out) {
  if (threadIdx.x != 0 || blockIdx.x != 0) return;
  double arm_loc = acc[0], arm_cls = acc[1], odm_loc = acc[2];
  double ce_pos = acc[3], neg_sum = acc[4];
  double armN = (double)iacc[0];
  long long Ni = 0;
  for (int b = 0; b < B; b++) Ni += poscnt[b];
  double N = (double)Ni;
  double class_loss = (ce_pos + neg_sum) / N;
  double loc_loss = odm_loc / N;
  double acls = 0.04 * arm_cls / armN;
  double aloc = arm_loc / armN;
  double total = class_loss + loc_loss + acls + aloc;
  out[0] = (float)total;
  out[1] = (float)class_loss;
  out[2] = (float)loc_loss;
  out[3] = (float)acls;
  out[4] = (float)aloc;
}

// ---------- launcher ----------

extern "C" void kernel_launch(void* const* d_in, const int* in_sizes, int n_in,
                              void* d_out, int out_size, void* d_ws, size_t ws_size,
                              hipStream_t stream) {
  const float* objectness = (const float*)d_in[0];
  const float* refine_loc = (const float*)d_in[1];
  const float* pred_conf  = (const float*)d_in[2];
  const float* pred_loc   = (const float*)d_in[3];
  const float* anchors    = (const float*)d_in[4];  // [1,A,4]
  const float* gt_boxes   = (const float*)d_in[5];
  const int*   gt_labels  = (const int*)d_in[6];

  int A = in_sizes[4] / 4;
  int B = in_sizes[0] / (A * 2);
  int C = (int)(in_sizes[2] / ((long long)B * A));
  int M = in_sizes[5] / (B * 4);

  char* ws = (char*)d_ws;
  // [0,64): double acc[5] (arm_loc, arm_cls, odm_loc, ce_pos, neg_sum)
  // [64,128): int iacc (arm_N)
  // [128,128+4B): int poscnt[B]
  // [512,...): best_anchor1[B*M], best_anchor2[B*M], then negl[B*A]
  double* acc = (double*)ws;
  int* iacc = (int*)(ws + 64);
  int* poscnt = (int*)(ws + 128);
  int* ba1 = (int*)(ws + 512);
  int* ba2 = (int*)(ws + 512 + (size_t)B * M * 4);
  size_t negl_off = 512 + 2 * (size_t)B * M * 4;
  negl_off = (negl_off + 255) & ~(size_t)255;
  float* negl = (float*)(ws + negl_off);

  hipMemsetAsync(d_ws, 0, 512, stream);

  gt_best_anchor_kernel<false><<<B * M, 256, 0, stream>>>(gt_boxes, anchors, anchors, ba1, B, M, A);
  gt_best_anchor_kernel<true><<<B * M, 256, 0, stream>>>(gt_boxes, anchors, refine_loc, ba2, B, M, A);

  dim3 grid(16, B);  // 512 blocks, grid-stride over A
  loss_kernel<<<grid, 256, 0, stream>>>(gt_boxes, gt_labels, anchors, refine_loc,
                                        objectness, pred_conf, pred_loc, ba1, ba2,
                                        acc, iacc, poscnt, negl, B, M, A, C);

  hardneg_kernel<<<B, 1024, 0, stream>>>(negl, poscnt, acc, A);

  finalize_kernel<<<1, 1, 0, stream>>>(acc, iacc, poscnt, B, (float*)d_out);
}